// Round 11
// baseline (362.468 us; speedup 1.0000x reference)
//
#include <hip/hip_runtime.h>
#include <hip/hip_bf16.h>

#define N_HEADS 16
#define D_MODEL 1024
#define D_K     64
#define B_SZ    2
#define T_LEN   2048
#define M_ROWS  (B_SZ * T_LEN)   // 4096

typedef __bf16 bf16;
typedef __bf16 bf16x4 __attribute__((ext_vector_type(4)));
typedef __bf16 bf16x8 __attribute__((ext_vector_type(8)));
typedef float  f32x4  __attribute__((ext_vector_type(4)));
typedef unsigned int u32;

// async global->LDS, 16B per lane. LDS dest = wave-uniform base + lane*16.
__device__ __forceinline__ void gload16(const bf16* g, bf16* l) {
    __builtin_amdgcn_global_load_lds(
        (const __attribute__((address_space(1))) u32*)g,
        (__attribute__((address_space(3))) u32*)l, 16, 0, 0);
}

// counted-vmcnt + raw barrier (T4): keep prefetch loads in flight across the
// barrier instead of __syncthreads()'s vmcnt(0) drain.
#define WAIT_VM(N) asm volatile("s_waitcnt vmcnt(" #N ")" ::: "memory")

// ---------------------------------------------------------------------------
// Weight transpose + f32->bf16 (z selects which W): W [K,N] -> Wt [N,K] bf16
// ---------------------------------------------------------------------------
__global__ void wt_kernel(const float* __restrict__ W0, const float* __restrict__ W1,
                          const float* __restrict__ W2, const float* __restrict__ W3,
                          bf16* __restrict__ T0, bf16* __restrict__ T1,
                          bf16* __restrict__ T2, bf16* __restrict__ T3) {
    __shared__ float tile[32][33];
    const int z = blockIdx.z;
    const float* W = (z == 0) ? W0 : (z == 1) ? W1 : (z == 2) ? W2 : W3;
    bf16* Wt       = (z == 0) ? T0 : (z == 1) ? T1 : (z == 2) ? T2 : T3;
    const int tx = threadIdx.x, ty = threadIdx.y;
    const int x0 = blockIdx.x * 32, y0 = blockIdx.y * 32;
    for (int yy = ty; yy < 32; yy += 8)
        tile[yy][tx] = W[(size_t)(y0 + yy) * D_MODEL + x0 + tx];
    __syncthreads();
    for (int yy = ty; yy < 32; yy += 8)
        Wt[(size_t)(x0 + yy) * D_MODEL + y0 + tx] = (bf16)tile[tx][yy];
}

// ---------------------------------------------------------------------------
// Fused f32->bf16 convert for q,k,v (blockIdx.y selects array). 8 elems/thr.
// ---------------------------------------------------------------------------
__global__ void conv3_kernel(const float* __restrict__ q, const float* __restrict__ k,
                             const float* __restrict__ v,
                             bf16* __restrict__ qb, bf16* __restrict__ kb,
                             bf16* __restrict__ vb) {
    const int z = blockIdx.y;
    const float* X = (z == 0) ? q : (z == 1) ? k : v;
    bf16* Y        = (z == 0) ? qb : (z == 1) ? kb : vb;
    const size_t i = ((size_t)blockIdx.x * 256 + threadIdx.x) * 8;
    const float4 v0 = *(const float4*)&X[i];
    const float4 v1 = *(const float4*)&X[i + 4];
    bf16x8 y;
    y[0]=(bf16)v0.x; y[1]=(bf16)v0.y; y[2]=(bf16)v0.z; y[3]=(bf16)v0.w;
    y[4]=(bf16)v1.x; y[5]=(bf16)v1.y; y[6]=(bf16)v1.z; y[7]=(bf16)v1.w;
    *(bf16x8*)&Y[i] = y;
}

// ---------------------------------------------------------------------------
// Fused QKV projection: global_load_lds both operands, TRIPLE-buffered LDS
// (prefetch distance 2, counted vmcnt), chunked XCD swizzle, FUSED row norms.
// launch_bounds(256,3): (256,4) spilled acc to scratch (round 6).
// ---------------------------------------------------------------------------
__global__ __launch_bounds__(256, 3) void proj_kernel(
    const bf16* __restrict__ qb, const bf16* __restrict__ kb, const bf16* __restrict__ vb,
    const bf16* __restrict__ WtQ, const bf16* __restrict__ WtK, const bf16* __restrict__ WtV,
    const float* __restrict__ bqp, const float* __restrict__ bkp, const float* __restrict__ bvp,
    bf16* __restrict__ qh, bf16* __restrict__ kh, bf16* __restrict__ vt,
    float* __restrict__ nq, float* __restrict__ nk)
{
    __shared__ bf16 As[3][128 * 32];   // 8KB each
    __shared__ bf16 Bs[3][128 * 32];

    const int hw      = blockIdx.x;
    const int logical = (hw & 7) * 96 + (hw >> 3);
    const int z       = logical >> 8;
    const int r       = logical & 255;
    const int m0      = (r >> 3) * 128;
    const int n0      = (r & 7) * 128;

    const bf16*  A    = (z == 0) ? qb  : (z == 1) ? kb  : vb;
    const bf16*  Bt   = (z == 0) ? WtQ : (z == 1) ? WtK : WtV;
    const float* bias = (z == 0) ? bqp : (z == 1) ? bkp : bvp;
    bf16* Out         = (z == 0) ? qh  : (z == 1) ? kh  : vt;

    const int tid = threadIdx.x, lane = tid & 63, w = tid >> 6;
    const int wm = w >> 1, wn = w & 1, g = lane >> 4, c = lane & 15;

    const int srow = w * 32 + (lane >> 2);     // staging row (first half)
    const int scol = (lane & 3) * 8;           // staging col
    const bf16* Ag = A  + (size_t)(m0 + srow) * D_MODEL + scol;
    const bf16* Bg = Bt + (size_t)(n0 + srow) * D_MODEL + scol;

    f32x4 acc[4][4] = {};

#define PSTAGE(buf, kk)                                                         \
    do {                                                                        \
        gload16(Ag + (kk),                  &As[buf][(w * 32) * 32]);           \
        gload16(Ag + 16 * D_MODEL + (kk),   &As[buf][(w * 32 + 16) * 32]);      \
        gload16(Bg + (kk),                  &Bs[buf][(w * 32) * 32]);           \
        gload16(Bg + 16 * D_MODEL + (kk),   &Bs[buf][(w * 32 + 16) * 32]);      \
    } while (0)

    PSTAGE(0, 0);
    PSTAGE(1, 32);
    WAIT_VM(4);                       // tile 0 landed; tile 1 still in flight
    __builtin_amdgcn_s_barrier();

    int cur = 0;
    for (int t = 0; t < 32; ++t) {
        if (t + 2 < 32) {
            int pre = cur + 2; if (pre >= 3) pre -= 3;
            PSTAGE(pre, (t + 2) * 32);
        }

        bf16x8 a[4], b[4];
        #pragma unroll
        for (int i = 0; i < 4; i++) a[i] = *(const bf16x8*)&As[cur][(wm*64 + i*16 + c) * 32 + g*8];
        #pragma unroll
        for (int j = 0; j < 4; j++) b[j] = *(const bf16x8*)&Bs[cur][(wn*64 + j*16 + c) * 32 + g*8];

        __builtin_amdgcn_s_setprio(1);
        if (z != 2) {
            #pragma unroll
            for (int i = 0; i < 4; i++)
                #pragma unroll
                for (int j = 0; j < 4; j++)
                    acc[i][j] = __builtin_amdgcn_mfma_f32_16x16x32_bf16(a[i], b[j], acc[i][j], 0, 0, 0);
        } else {
            #pragma unroll
            for (int i = 0; i < 4; i++)
                #pragma unroll
                for (int j = 0; j < 4; j++)
                    acc[i][j] = __builtin_amdgcn_mfma_f32_16x16x32_bf16(b[j], a[i], acc[i][j], 0, 0, 0);
        }
        __builtin_amdgcn_s_setprio(0);

        if (t + 2 < 32) { WAIT_VM(4); }   // next tile landed, t+2's 4 in flight
        else            { WAIT_VM(0); }
        __builtin_amdgcn_s_barrier();
        cur = (cur + 1 == 3) ? 0 : cur + 1;
    }
#undef PSTAGE

    if (z != 2) {
        float* nrm = (z == 0) ? nq : nk;
        const int h_ = (n0 >> 6) + wn;      // this wave's head
        #pragma unroll
        for (int i = 0; i < 4; i++)
            #pragma unroll
            for (int r4 = 0; r4 < 4; r4++) {
                const int mrow = m0 + wm*64 + i*16 + g*4 + r4;
                const int b_ = mrow >> 11, t_ = mrow & (T_LEN - 1);
                float ss = 0.f;
                #pragma unroll
                for (int j = 0; j < 4; j++) {
                    const int ncol = n0 + wn*64 + j*16 + c;
                    const float y = acc[i][j][r4] + bias[ncol];
                    Out[(((size_t)(b_*N_HEADS + h_))*T_LEN + t_)*D_K + j*16 + c] = (bf16)y;
                    ss += y * y;
                }
                ss += __shfl_xor(ss, 1, 64);
                ss += __shfl_xor(ss, 2, 64);
                ss += __shfl_xor(ss, 4, 64);
                ss += __shfl_xor(ss, 8, 64);
                if (c == 0)
                    nrm[((size_t)(b_*N_HEADS + h_))*T_LEN + t_] = sqrtf(ss);
            }
    } else {
        #pragma unroll
        for (int i = 0; i < 4; i++)
            #pragma unroll
            for (int j = 0; j < 4; j++)
                #pragma unroll
                for (int r4 = 0; r4 < 4; r4++) {
                    const int nrow = n0 + wn*64 + j*16 + g*4 + r4;
                    const int mcol = m0 + wm*64 + i*16 + c;
                    const float y = acc[i][j][r4] + bias[nrow];
                    const int b_ = mcol >> 11, t_ = mcol & (T_LEN - 1);
                    const int h2 = nrow >> 6,  d_ = nrow & (D_K - 1);
                    Out[(((size_t)(b_*N_HEADS + h2))*D_K + d_)*T_LEN + t_] = (bf16)y;
                }
    }
}

// ---------------------------------------------------------------------------
// Flash attention v8: K never touches LDS — fragments loaded global->reg
// (L2-resident, XCD-swizzled) with 1-tile software prefetch. V stays LDS
// (double-buffered, XOR-swizzled gload_lds). LDS bytes/wave/tile 20KB->12KB;
// LDS footprint 66KB->34KB. Fixed-max softmax, MFMA row-sum, 8 waves/block.
// vmcnt discipline: V gload issued FIRST (pinned by sched_barrier), then
// kr/NK reg loads -> WAIT_VM(12) at barrier = V landed, 12 reg-loads fly.
// ---------------------------------------------------------------------------
#define KVB 64

__global__ __launch_bounds__(512, 4) void attn_kernel(
    const bf16* __restrict__ qh, const bf16* __restrict__ kh, const bf16* __restrict__ vt,
    const float* __restrict__ nq, const float* __restrict__ nk,
    const float* __restrict__ alpha, bf16* __restrict__ ao)
{
    __shared__ bf16 Vs[2][KVB * D_K];      // 8KB each
    __shared__ bf16 plds[8][16][72];       // per-wave P[q][k] (same-wave only)

    const int bid     = blockIdx.x;
    const int logical = (bid & 7) * 64 + (bid >> 3);   // 4 heads per XCD
    const int bh      = logical >> 4;
    const int q0b     = (logical & 15) * 128;

    const int tid  = threadIdx.x;
    const int w    = tid >> 6;
    const int lane = tid & 63;
    const int g    = lane >> 4, c = lane & 15;
    const int myq  = q0b + w * 16 + c;
    const int sw   = (c & 7) << 4;         // V read-side XOR swizzle (bytes)

    // V staging geometry: slot s = tid; row = s>>3, unit = s&7
    const int srow = tid >> 3;
    const int sgb  = (((tid & 7) ^ (srow & 7)) << 4);

    const bf16* Q  = qh + (size_t)bh * T_LEN * D_K;
    const bf16* K  = kh + (size_t)bh * T_LEN * D_K;
    const bf16* V  = vt + (size_t)bh * D_K * T_LEN;
    const float* NK = nk + (size_t)bh * T_LEN;

    const float al   = alpha[bh & (N_HEADS - 1)];
    const float a4   = al * 4.0f * 1.44269504f;     // into log2 domain
    const float negM = -(al * 1.44269504f) - 1e-4f; // |score|*log2e <= al*log2e

    const bf16x8 bq0 = *(const bf16x8*)&Q[(size_t)myq * D_K + g*8];
    const bf16x8 bq1 = *(const bf16x8*)&Q[(size_t)myq * D_K + 32 + g*8];
    const float nq_own = nq[(size_t)bh * T_LEN + myq];

    bf16x8 ones;
    #pragma unroll
    for (int e = 0; e < 8; e++) ones[e] = (bf16)1.0f;

    f32x4 o[4] = {};    // O^T: lane owns q col; d = f*16 + g*4 + r
    f32x4 o4  = {};     // row-sum accumulator (all r equal)

#define VSTAGE(buf, kn)                                                                           \
    gload16((const bf16*)((const char*)&V[(size_t)srow * T_LEN + (kn)] + sgb), &Vs[buf][w * 512])

// K fragments for tile starting at kn: direct global->reg (round-2 layout)
#define KLOAD(kn)                                                               \
    do {                                                                        \
        _Pragma("unroll")                                                       \
        for (int cb = 0; cb < 4; cb++) {                                        \
            const bf16* Kr = &K[(size_t)((kn) + cb*16 + c) * D_K];              \
            kr0[cb] = *(const bf16x8*)&Kr[g*8];                                 \
            kr1[cb] = *(const bf16x8*)&Kr[32 + g*8];                            \
        }                                                                       \
    } while (0)

#define NKLOAD(kn)                                                              \
    do {                                                                        \
        _Pragma("unroll")                                                       \
        for (int cb = 0; cb < 4; cb++)                                          \
            nk4[cb] = *(const float4*)&NK[(kn) + cb*16 + g*4];                  \
    } while (0)

// softmax quadrant: x = S*rd2 + negM; p = exp2(x); pack to plds
#define SM(cb)                                                                  \
    do {                                                                        \
        bf16x4 pk;                                                              \
        pk[0] = (bf16)__builtin_amdgcn_exp2f(                                   \
            __builtin_fmaf(S[cb][0], rd2[cb][0], negM));                        \
        pk[1] = (bf16)__builtin_amdgcn_exp2f(                                   \
            __builtin_fmaf(S[cb][1], rd2[cb][1], negM));                        \
        pk[2] = (bf16)__builtin_amdgcn_exp2f(                                   \
            __builtin_fmaf(S[cb][2], rd2[cb][2], negM));                        \
        pk[3] = (bf16)__builtin_amdgcn_exp2f(                                   \
            __builtin_fmaf(S[cb][3], rd2[cb][3], negM));                        \
        *(bf16x4*)&plds[w][c][(cb)*16 + g*4] = pk;                              \
    } while (0)

// PV half ks: P from plds (1 ds_read), V from preloaded regs
#define PV(ks)                                                                  \
    do {                                                                        \
        const bf16x8 pb = *(const bf16x8*)&plds[w][c][(ks)*32 + g*8];           \
        __builtin_amdgcn_s_setprio(1);                                          \
        _Pragma("unroll")                                                       \
        for (int f = 0; f < 4; f++)                                             \
            o[f] = __builtin_amdgcn_mfma_f32_16x16x32_bf16(vbr[ks][f], pb, o[f], 0, 0, 0); \
        o4 = __builtin_amdgcn_mfma_f32_16x16x32_bf16(ones, pb, o4, 0, 0, 0);    \
        __builtin_amdgcn_s_setprio(0);                                          \
    } while (0)

    bf16x8 kr0[4], kr1[4];
    float4 nk4[4];

    // prologue: V(0) staged, K(0)/NK(0) to regs
    VSTAGE(0, 0);
    KLOAD(0);
    NKLOAD(0);
    WAIT_VM(0);
    __builtin_amdgcn_s_barrier();

    const int NT = T_LEN / KVB;   // 32
    int cur = 0;
    for (int t = 0; t < NT; ++t) {
        const int kn = (t + 1) * KVB;

        // ---- S^T = K.Q^T from registers ----
        f32x4 S[4];
        __builtin_amdgcn_s_setprio(1);
        #pragma unroll
        for (int cb = 0; cb < 4; cb++) {
            f32x4 s = {};
            s = __builtin_amdgcn_mfma_f32_16x16x32_bf16(kr0[cb], bq0, s, 0, 0, 0);
            s = __builtin_amdgcn_mfma_f32_16x16x32_bf16(kr1[cb], bq1, s, 0, 0, 0);
            S[cb] = s;
        }
        __builtin_amdgcn_s_setprio(0);

        // ---- rd2 = a4/(nq+nk)^2 (consumes nk4 before the t+1 reload) ----
        float rd2[4][4];
        #pragma unroll
        for (int cb = 0; cb < 4; cb++) {
            const float nkr[4] = {nk4[cb].x, nk4[cb].y, nk4[cb].z, nk4[cb].w};
            #pragma unroll
            for (int r = 0; r < 4; r++) {
                const float den = nq_own + nkr[r];
                const float rr  = __builtin_amdgcn_rcpf(den);
                rd2[cb][r] = (a4 * rr) * rr;
            }
        }

        // ---- prefetch t+1: V gload FIRST (pinned), then kr/NK reg loads ----
        if (t + 1 < NT) VSTAGE(cur ^ 1, kn);
        __builtin_amdgcn_sched_barrier(0);
        if (t + 1 < NT) { KLOAD(kn); NKLOAD(kn); }

        // ---- V fragment preload from LDS (latency hides under softmax) ----
        bf16x8 vbr[2][4];
        #pragma unroll
        for (int ks = 0; ks < 2; ks++)
            #pragma unroll
            for (int f = 0; f < 4; f++) {
                const char* vbase = (const char*)&Vs[cur][(size_t)(f*16 + c) * D_K];
                vbr[ks][f] = *(const bf16x8*)(vbase + ((ks*64 + g*16) ^ sw));
            }

        // ---- pipelined softmax / PV ----
        SM(0); SM(1);
        PV(0);
        SM(2); SM(3);
        PV(1);

        // counted drain: V(t+1) landed; 12 reg loads (kr8 + nk4) stay in flight
        if (t + 1 < NT) { WAIT_VM(12); }
        else            { WAIT_VM(0); }
        __builtin_amdgcn_s_barrier();
        cur ^= 1;
    }
#undef VSTAGE
#undef KLOAD
#undef NKLOAD
#undef SM
#undef PV

    const int b_ = bh >> 4, h_ = bh & 15;
    const float inv = 1.0f / o4[0];
    #pragma unroll
    for (int f = 0; f < 4; f++) {
        bf16x4 w4;
        #pragma unroll
        for (int r = 0; r < 4; r++) w4[r] = (bf16)(o[f][r] * inv);
        *(bf16x4*)&ao[((size_t)(b_*T_LEN + myq))*D_MODEL + h_*D_K + f*16 + g*4] = w4;
    }
}

// ---------------------------------------------------------------------------
// Final GEMM: out_f32[4096,1024] = ao_bf16 @ WtO^T + bo.  BM=64, BN=128,
// TRIPLE-buffered (dist-2 prefetch, counted vmcnt), chunked XCD swizzle.
// ---------------------------------------------------------------------------
__global__ __launch_bounds__(256, 4) void gemmo_kernel(
    const bf16* __restrict__ A, const bf16* __restrict__ Bt,
    const float* __restrict__ bias, float* __restrict__ Out)
{
    __shared__ bf16 As[3][64 * 32];
    __shared__ bf16 Bs[3][128 * 32];

    const int hw      = blockIdx.x;
    const int logical = (hw & 7) * 64 + (hw >> 3);
    const int m0      = (logical >> 3) * 64;
    const int n0      = (logical & 7) * 128;

    const int tid = threadIdx.x, lane = tid & 63, w = tid >> 6;
    const int wm = w >> 1, wn = w & 1, g = lane >> 4, c = lane & 15;

    const int arow = w * 16 + (lane >> 2);
    const int brow = w * 32 + (lane >> 2);
    const int scol = (lane & 3) * 8;
    const bf16* Ag = A  + (size_t)(m0 + arow) * D_MODEL + scol;
    const bf16* Bg = Bt + (size_t)(n0 + brow) * D_MODEL + scol;

    f32x4 acc[2][4] = {};

#define OSTAGE(buf, kk)                                                         \
    do {                                                                        \
        gload16(Ag + (kk),                &As[buf][(w * 16) * 32]);             \
        gload16(Bg + (kk),                &Bs[buf][(w * 32) * 32]);             \
        gload16(Bg + 16 * D_MODEL + (kk), &Bs[buf][(w * 32 + 16) * 32]);        \
    } while (0)

    OSTAGE(0, 0);
    OSTAGE(1, 32);
    WAIT_VM(3);
    __builtin_amdgcn_s_barrier();

    int cur = 0;
    for (int t = 0; t < 32; ++t) {
        if (t + 2 < 32) {
            int pre = cur + 2; if (pre >= 3) pre -= 3;
            OSTAGE(pre, (t + 2) * 32);
        }

        bf16x8 a[2], b[4];
        #pragma unroll
        for (int i = 0; i < 2; i++) a[i] = *(const bf16x8*)&As[cur][(wm*32 + i*16 + c) * 32 + g*8];
        #pragma unroll
        for (int j = 0; j < 4; j++) b[j] = *(const bf16x8*)&Bs[cur][(wn*64 + j*16 + c) * 32 + g*8];

        __builtin_amdgcn_s_setprio(1);
        #pragma unroll
        for (int i = 0; i < 2; i++)
            #pragma unroll
            for (int j = 0; j < 4; j++)
                acc[i][j] = __builtin_amdgcn_mfma_f32_16x16x32_bf16(a[i], b[j], acc[i][j], 0, 0, 0);
        __builtin_amdgcn_s_setprio(0);

        if (t + 2 < 32) { WAIT_VM(3); }
        else            { WAIT_VM(0); }
        __builtin_amdgcn_s_barrier();
        cur = (cur + 1 == 3) ? 0 : cur + 1;
    }
#undef OSTAGE

    #pragma unroll
    for (int i = 0; i < 2; i++)
        #pragma unroll
        for (int j = 0; j < 4; j++) {
            const int ncol = n0 + wn*64 + j*16 + c;
            const float bb = bias[ncol];
            #pragma unroll
            for (int r = 0; r < 4; r++) {
                const int mrow = m0 + wm*32 + i*16 + g*4 + r;
                Out[(size_t)mrow * D_MODEL + ncol] = acc[i][j][r] + bb;
            }
        }
}

// ---------------------------------------------------------------------------
extern "C" void kernel_launch(void* const* d_in, const int* in_sizes, int n_in,
                              void* d_out, int out_size, void* d_ws, size_t ws_size,
                              hipStream_t stream) {
    const float* q     = (const float*)d_in[0];
    const float* k     = (const float*)d_in[1];
    const float* v     = (const float*)d_in[2];
    const float* Wq    = (const float*)d_in[3];
    const float* bq    = (const float*)d_in[4];
    const float* Wk    = (const float*)d_in[5];
    const float* bk    = (const float*)d_in[6];
    const float* Wv    = (const float*)d_in[7];
    const float* bv    = (const float*)d_in[8];
    const float* Wo    = (const float*)d_in[9];
    const float* bo    = (const float*)d_in[10];
    const float* alpha = (const float*)d_in[11];

    char* ws = (char*)d_ws;
    const size_t WBYTES = (size_t)D_MODEL * D_MODEL * sizeof(bf16);                // 2MB
    const size_t HBYTES = (size_t)B_SZ * N_HEADS * T_LEN * D_K * sizeof(bf16);     // 8MB
    const size_t NBYTES = (size_t)B_SZ * N_HEADS * T_LEN * sizeof(float);          // 256KB
    bf16* WtQ = (bf16*)ws;  ws += WBYTES;
    bf16* WtK = (bf16*)ws;  ws += WBYTES;
    bf16* WtV = (bf16*)ws;  ws += WBYTES;
    bf16* WtO = (bf16*)ws;  ws += WBYTES;
    bf16* qh  = (bf16*)ws;  ws += HBYTES;
    bf16* kh  = (bf16*)ws;  ws += HBYTES;
    bf16* vt  = (bf16*)ws;  ws += HBYTES;
    float* nq = (float*)ws; ws += NBYTES;
    float* nk = (float*)ws; ws += NBYTES;
    bf16* ao  = (bf16*)ws;  ws += HBYTES;   // attn out [B,T,D] bf16
    bf16* qb  = (bf16*)ws;  ws += HBYTES;   // q bf16
    bf16* kb  = (bf16*)ws;  ws += HBYTES;   // k bf16
    bf16* vb  = ao;                          // alias: vb dead before attn writes ao

    wt_kernel<<<dim3(32, 32, 4), dim3(32, 8), 0, stream>>>(
        Wq, Wk, Wv, Wo, WtQ, WtK, WtV, WtO);

    conv3_kernel<<<dim3(M_ROWS * D_MODEL / 8 / 256, 3), 256, 0, stream>>>(
        q, k, v, qb, kb, vb);

    proj_kernel<<<768, 256, 0, stream>>>(
        qb, kb, vb, WtQ, WtK, WtV, bq, bk, bv, qh, kh, vt, nq, nk);

    attn_kernel<<<512, 512, 0, stream>>>(qh, kh, vt, nq, nk, alpha, ao);

    gemmo_kernel<<<512, 256, 0, stream>>>(ao, WtO, bo, (float*)d_out);
}

// Round 12
// 149.428 us; speedup vs baseline: 2.4257x; 2.4257x over previous
//
#include <hip/hip_runtime.h>
#include <hip/hip_bf16.h>

#define N_HEADS 16
#define D_MODEL 1024
#define D_K     64
#define B_SZ    2
#define T_LEN   2048
#define M_ROWS  (B_SZ * T_LEN)   // 4096

typedef __bf16 bf16;
typedef __bf16 bf16x4 __attribute__((ext_vector_type(4)));
typedef __bf16 bf16x8 __attribute__((ext_vector_type(8)));
typedef float  f32x4  __attribute__((ext_vector_type(4)));
typedef unsigned int u32;

// async global->LDS, 16B per lane. LDS dest = wave-uniform base + lane*16.
__device__ __forceinline__ void gload16(const bf16* g, bf16* l) {
    __builtin_amdgcn_global_load_lds(
        (const __attribute__((address_space(1))) u32*)g,
        (__attribute__((address_space(3))) u32*)l, 16, 0, 0);
}

// counted-vmcnt + raw barrier (T4): keep prefetch loads in flight across the
// barrier instead of __syncthreads()'s vmcnt(0) drain.
#define WAIT_VM(N) asm volatile("s_waitcnt vmcnt(" #N ")" ::: "memory")

// ---------------------------------------------------------------------------
// Weight transpose + f32->bf16 (z selects which W): W [K,N] -> Wt [N,K] bf16
// ---------------------------------------------------------------------------
__global__ void wt_kernel(const float* __restrict__ W0, const float* __restrict__ W1,
                          const float* __restrict__ W2, const float* __restrict__ W3,
                          bf16* __restrict__ T0, bf16* __restrict__ T1,
                          bf16* __restrict__ T2, bf16* __restrict__ T3) {
    __shared__ float tile[32][33];
    const int z = blockIdx.z;
    const float* W = (z == 0) ? W0 : (z == 1) ? W1 : (z == 2) ? W2 : W3;
    bf16* Wt       = (z == 0) ? T0 : (z == 1) ? T1 : (z == 2) ? T2 : T3;
    const int tx = threadIdx.x, ty = threadIdx.y;
    const int x0 = blockIdx.x * 32, y0 = blockIdx.y * 32;
    for (int yy = ty; yy < 32; yy += 8)
        tile[yy][tx] = W[(size_t)(y0 + yy) * D_MODEL + x0 + tx];
    __syncthreads();
    for (int yy = ty; yy < 32; yy += 8)
        Wt[(size_t)(x0 + yy) * D_MODEL + y0 + tx] = (bf16)tile[tx][yy];
}

// ---------------------------------------------------------------------------
// Fused f32->bf16 convert for q,k,v (blockIdx.y selects array). 8 elems/thr.
// ---------------------------------------------------------------------------
__global__ void conv3_kernel(const float* __restrict__ q, const float* __restrict__ k,
                             const float* __restrict__ v,
                             bf16* __restrict__ qb, bf16* __restrict__ kb,
                             bf16* __restrict__ vb) {
    const int z = blockIdx.y;
    const float* X = (z == 0) ? q : (z == 1) ? k : v;
    bf16* Y        = (z == 0) ? qb : (z == 1) ? kb : vb;
    const size_t i = ((size_t)blockIdx.x * 256 + threadIdx.x) * 8;
    const float4 v0 = *(const float4*)&X[i];
    const float4 v1 = *(const float4*)&X[i + 4];
    bf16x8 y;
    y[0]=(bf16)v0.x; y[1]=(bf16)v0.y; y[2]=(bf16)v0.z; y[3]=(bf16)v0.w;
    y[4]=(bf16)v1.x; y[5]=(bf16)v1.y; y[6]=(bf16)v1.z; y[7]=(bf16)v1.w;
    *(bf16x8*)&Y[i] = y;
}

// ---------------------------------------------------------------------------
// Fused QKV projection: global_load_lds both operands, TRIPLE-buffered LDS
// (prefetch distance 2, counted vmcnt), chunked XCD swizzle, FUSED row norms.
// launch_bounds(256,3): (256,4) spilled acc to scratch (round 6).
// ---------------------------------------------------------------------------
__global__ __launch_bounds__(256, 3) void proj_kernel(
    const bf16* __restrict__ qb, const bf16* __restrict__ kb, const bf16* __restrict__ vb,
    const bf16* __restrict__ WtQ, const bf16* __restrict__ WtK, const bf16* __restrict__ WtV,
    const float* __restrict__ bqp, const float* __restrict__ bkp, const float* __restrict__ bvp,
    bf16* __restrict__ qh, bf16* __restrict__ kh, bf16* __restrict__ vt,
    float* __restrict__ nq, float* __restrict__ nk)
{
    __shared__ bf16 As[3][128 * 32];   // 8KB each
    __shared__ bf16 Bs[3][128 * 32];

    const int hw      = blockIdx.x;
    const int logical = (hw & 7) * 96 + (hw >> 3);
    const int z       = logical >> 8;
    const int r       = logical & 255;
    const int m0      = (r >> 3) * 128;
    const int n0      = (r & 7) * 128;

    const bf16*  A    = (z == 0) ? qb  : (z == 1) ? kb  : vb;
    const bf16*  Bt   = (z == 0) ? WtQ : (z == 1) ? WtK : WtV;
    const float* bias = (z == 0) ? bqp : (z == 1) ? bkp : bvp;
    bf16* Out         = (z == 0) ? qh  : (z == 1) ? kh  : vt;

    const int tid = threadIdx.x, lane = tid & 63, w = tid >> 6;
    const int wm = w >> 1, wn = w & 1, g = lane >> 4, c = lane & 15;

    const int srow = w * 32 + (lane >> 2);     // staging row (first half)
    const int scol = (lane & 3) * 8;           // staging col
    const bf16* Ag = A  + (size_t)(m0 + srow) * D_MODEL + scol;
    const bf16* Bg = Bt + (size_t)(n0 + srow) * D_MODEL + scol;

    f32x4 acc[4][4] = {};

#define PSTAGE(buf, kk)                                                         \
    do {                                                                        \
        gload16(Ag + (kk),                  &As[buf][(w * 32) * 32]);           \
        gload16(Ag + 16 * D_MODEL + (kk),   &As[buf][(w * 32 + 16) * 32]);      \
        gload16(Bg + (kk),                  &Bs[buf][(w * 32) * 32]);           \
        gload16(Bg + 16 * D_MODEL + (kk),   &Bs[buf][(w * 32 + 16) * 32]);      \
    } while (0)

    PSTAGE(0, 0);
    PSTAGE(1, 32);
    WAIT_VM(4);                       // tile 0 landed; tile 1 still in flight
    __builtin_amdgcn_s_barrier();

    int cur = 0;
    for (int t = 0; t < 32; ++t) {
        if (t + 2 < 32) {
            int pre = cur + 2; if (pre >= 3) pre -= 3;
            PSTAGE(pre, (t + 2) * 32);
        }

        bf16x8 a[4], b[4];
        #pragma unroll
        for (int i = 0; i < 4; i++) a[i] = *(const bf16x8*)&As[cur][(wm*64 + i*16 + c) * 32 + g*8];
        #pragma unroll
        for (int j = 0; j < 4; j++) b[j] = *(const bf16x8*)&Bs[cur][(wn*64 + j*16 + c) * 32 + g*8];

        __builtin_amdgcn_s_setprio(1);
        if (z != 2) {
            #pragma unroll
            for (int i = 0; i < 4; i++)
                #pragma unroll
                for (int j = 0; j < 4; j++)
                    acc[i][j] = __builtin_amdgcn_mfma_f32_16x16x32_bf16(a[i], b[j], acc[i][j], 0, 0, 0);
        } else {
            #pragma unroll
            for (int i = 0; i < 4; i++)
                #pragma unroll
                for (int j = 0; j < 4; j++)
                    acc[i][j] = __builtin_amdgcn_mfma_f32_16x16x32_bf16(b[j], a[i], acc[i][j], 0, 0, 0);
        }
        __builtin_amdgcn_s_setprio(0);

        if (t + 2 < 32) { WAIT_VM(4); }   // next tile landed, t+2's 4 in flight
        else            { WAIT_VM(0); }
        __builtin_amdgcn_s_barrier();
        cur = (cur + 1 == 3) ? 0 : cur + 1;
    }
#undef PSTAGE

    if (z != 2) {
        float* nrm = (z == 0) ? nq : nk;
        const int h_ = (n0 >> 6) + wn;      // this wave's head
        #pragma unroll
        for (int i = 0; i < 4; i++)
            #pragma unroll
            for (int r4 = 0; r4 < 4; r4++) {
                const int mrow = m0 + wm*64 + i*16 + g*4 + r4;
                const int b_ = mrow >> 11, t_ = mrow & (T_LEN - 1);
                float ss = 0.f;
                #pragma unroll
                for (int j = 0; j < 4; j++) {
                    const int ncol = n0 + wn*64 + j*16 + c;
                    const float y = acc[i][j][r4] + bias[ncol];
                    Out[(((size_t)(b_*N_HEADS + h_))*T_LEN + t_)*D_K + j*16 + c] = (bf16)y;
                    ss += y * y;
                }
                ss += __shfl_xor(ss, 1, 64);
                ss += __shfl_xor(ss, 2, 64);
                ss += __shfl_xor(ss, 4, 64);
                ss += __shfl_xor(ss, 8, 64);
                if (c == 0)
                    nrm[((size_t)(b_*N_HEADS + h_))*T_LEN + t_] = sqrtf(ss);
            }
    } else {
        #pragma unroll
        for (int i = 0; i < 4; i++)
            #pragma unroll
            for (int j = 0; j < 4; j++)
                #pragma unroll
                for (int r4 = 0; r4 < 4; r4++) {
                    const int nrow = n0 + wn*64 + j*16 + g*4 + r4;
                    const int mcol = m0 + wm*64 + i*16 + c;
                    const float y = acc[i][j][r4] + bias[nrow];
                    const int b_ = mcol >> 11, t_ = mcol & (T_LEN - 1);
                    const int h2 = nrow >> 6,  d_ = nrow & (D_K - 1);
                    Out[(((size_t)(b_*N_HEADS + h2))*D_K + d_)*T_LEN + t_] = (bf16)y;
                }
    }
}

// ---------------------------------------------------------------------------
// Flash attention v7 (round-10 known-good): fixed-max softmax, MFMA row-sum,
// 8 waves/block, triple-buffered K/V (dist-2 prefetch, counted vmcnt),
// XOR-swizzled staging, XCD mapping, V-fragment preload + rd2 split.
// Round-11 lesson: K-in-registers spills at (512,4) — K stays in LDS.
// ---------------------------------------------------------------------------
#define KVB 64

__global__ __launch_bounds__(512, 4) void attn_kernel(
    const bf16* __restrict__ qh, const bf16* __restrict__ kh, const bf16* __restrict__ vt,
    const float* __restrict__ nq, const float* __restrict__ nk,
    const float* __restrict__ alpha, bf16* __restrict__ ao)
{
    __shared__ bf16 Ks[3][KVB * D_K];      // 8KB each
    __shared__ bf16 Vs[3][KVB * D_K];      // 8KB each
    __shared__ bf16 plds[8][16][72];       // per-wave P[q][k] (same-wave only)

    const int bid     = blockIdx.x;
    const int logical = (bid & 7) * 64 + (bid >> 3);   // 4 heads per XCD
    const int bh      = logical >> 4;
    const int q0b     = (logical & 15) * 128;

    const int tid  = threadIdx.x;
    const int w    = tid >> 6;
    const int lane = tid & 63;
    const int g    = lane >> 4, c = lane & 15;
    const int myq  = q0b + w * 16 + c;
    const int sw   = (c & 7) << 4;         // read-side XOR swizzle (bytes)

    // staging geometry: slot s = tid; row = s>>3, unit = s&7
    const int srow = tid >> 3;
    const int sgb  = (((tid & 7) ^ (srow & 7)) << 4);

    const bf16* Q  = qh + (size_t)bh * T_LEN * D_K;
    const bf16* K  = kh + (size_t)bh * T_LEN * D_K;
    const bf16* V  = vt + (size_t)bh * D_K * T_LEN;
    const float* NK = nk + (size_t)bh * T_LEN;

    const float al   = alpha[bh & (N_HEADS - 1)];
    const float a4   = al * 4.0f * 1.44269504f;     // into log2 domain
    const float negM = -(al * 1.44269504f) - 1e-4f; // |score|*log2e <= al*log2e

    const bf16x8 bq0 = *(const bf16x8*)&Q[(size_t)myq * D_K + g*8];
    const bf16x8 bq1 = *(const bf16x8*)&Q[(size_t)myq * D_K + 32 + g*8];
    const float nq_own = nq[(size_t)bh * T_LEN + myq];

    bf16x8 ones;
    #pragma unroll
    for (int e = 0; e < 8; e++) ones[e] = (bf16)1.0f;

    f32x4 o[4] = {};    // O^T: lane owns q col; d = f*16 + g*4 + r
    f32x4 o4  = {};     // row-sum accumulator (all r equal)

#define AKSTAGE(buf, kn)                                                                          \
    do {                                                                                          \
        gload16((const bf16*)((const char*)&K[(size_t)((kn) + srow) * D_K] + sgb), &Ks[buf][w * 512]); \
        gload16((const bf16*)((const char*)&V[(size_t)srow * T_LEN + (kn)] + sgb), &Vs[buf][w * 512]); \
    } while (0)

// softmax quadrant: x = S*rd2 + negM; p = exp2(x); pack to plds
#define SM(cb)                                                                  \
    do {                                                                        \
        bf16x4 pk;                                                              \
        pk[0] = (bf16)__builtin_amdgcn_exp2f(                                   \
            __builtin_fmaf(S[cb][0], rd2[cb][0], negM));                        \
        pk[1] = (bf16)__builtin_amdgcn_exp2f(                                   \
            __builtin_fmaf(S[cb][1], rd2[cb][1], negM));                        \
        pk[2] = (bf16)__builtin_amdgcn_exp2f(                                   \
            __builtin_fmaf(S[cb][2], rd2[cb][2], negM));                        \
        pk[3] = (bf16)__builtin_amdgcn_exp2f(                                   \
            __builtin_fmaf(S[cb][3], rd2[cb][3], negM));                        \
        *(bf16x4*)&plds[w][c][(cb)*16 + g*4] = pk;                              \
    } while (0)

// PV half ks: P from plds (1 ds_read), V from preloaded regs
#define PV(ks)                                                                  \
    do {                                                                        \
        const bf16x8 pb = *(const bf16x8*)&plds[w][c][(ks)*32 + g*8];           \
        __builtin_amdgcn_s_setprio(1);                                          \
        _Pragma("unroll")                                                       \
        for (int f = 0; f < 4; f++)                                             \
            o[f] = __builtin_amdgcn_mfma_f32_16x16x32_bf16(vbr[ks][f], pb, o[f], 0, 0, 0); \
        o4 = __builtin_amdgcn_mfma_f32_16x16x32_bf16(ones, pb, o4, 0, 0, 0);    \
        __builtin_amdgcn_s_setprio(0);                                          \
    } while (0)

    AKSTAGE(0, 0);
    AKSTAGE(1, KVB);
    WAIT_VM(2);                      // tile 0 landed; tile 1 still in flight
    __builtin_amdgcn_s_barrier();

    const int NT = T_LEN / KVB;   // 32
    int cur = 0;
    for (int t = 0; t < NT; ++t) {
        const int k0 = t * KVB;

        // NK preload FIRST (compiler's wait for them leaves prefetch in flight)
        float4 nk4[4];
        #pragma unroll
        for (int cb = 0; cb < 4; cb++) nk4[cb] = *(const float4*)&NK[k0 + cb*16 + g*4];
        __builtin_amdgcn_sched_barrier(0);

        // prefetch tile t+2
        if (t + 2 < NT) {
            int pre = cur + 2; if (pre >= 3) pre -= 3;
            AKSTAGE(pre, k0 + 2*KVB);
        }

        // ---- S^T = K.Q^T (all 4 quadrants) ----
        f32x4 S[4];
        __builtin_amdgcn_s_setprio(1);
        #pragma unroll
        for (int cb = 0; cb < 4; cb++) {
            const char* kbase = (const char*)&Ks[cur][(size_t)(cb*16 + c) * D_K];
            const bf16x8 ka = *(const bf16x8*)(kbase + ((g*16) ^ sw));
            const bf16x8 kb = *(const bf16x8*)(kbase + ((64 + g*16) ^ sw));
            f32x4 s = {};
            s = __builtin_amdgcn_mfma_f32_16x16x32_bf16(ka, bq0, s, 0, 0, 0);
            s = __builtin_amdgcn_mfma_f32_16x16x32_bf16(kb, bq1, s, 0, 0, 0);
            S[cb] = s;
        }
        __builtin_amdgcn_s_setprio(0);

        // ---- V fragment preload (LDS latency hides under rd2 + softmax) ----
        bf16x8 vbr[2][4];
        #pragma unroll
        for (int ks = 0; ks < 2; ks++)
            #pragma unroll
            for (int f = 0; f < 4; f++) {
                const char* vbase = (const char*)&Vs[cur][(size_t)(f*16 + c) * D_K];
                vbr[ks][f] = *(const bf16x8*)(vbase + ((ks*64 + g*16) ^ sw));
            }

        // ---- rd2 = a4 / (nq+nk)^2 for the whole tile (rcp chain up front) ----
        float rd2[4][4];
        #pragma unroll
        for (int cb = 0; cb < 4; cb++) {
            const float nkr[4] = {nk4[cb].x, nk4[cb].y, nk4[cb].z, nk4[cb].w};
            #pragma unroll
            for (int r = 0; r < 4; r++) {
                const float den = nq_own + nkr[r];
                const float rr  = __builtin_amdgcn_rcpf(den);
                rd2[cb][r] = (a4 * rr) * rr;
            }
        }

        // ---- pipelined softmax / PV ----
        SM(0); SM(1);
        PV(0);
        SM(2); SM(3);
        PV(1);

        // counted drain: tile t+1 ready, t+2's 2 loads stay in flight
        if (t + 2 < NT) { WAIT_VM(2); }
        else            { WAIT_VM(0); }
        __builtin_amdgcn_s_barrier();
        cur = (cur + 1 == 3) ? 0 : cur + 1;
    }
#undef AKSTAGE
#undef SM
#undef PV

    const int b_ = bh >> 4, h_ = bh & 15;
    const float inv = 1.0f / o4[0];
    #pragma unroll
    for (int f = 0; f < 4; f++) {
        bf16x4 w4;
        #pragma unroll
        for (int r = 0; r < 4; r++) w4[r] = (bf16)(o[f][r] * inv);
        *(bf16x4*)&ao[((size_t)(b_*T_LEN + myq))*D_MODEL + h_*D_K + f*16 + g*4] = w4;
    }
}

// ---------------------------------------------------------------------------
// Final GEMM: out_f32[4096,1024] = ao_bf16 @ WtO^T + bo.  BM=64, BN=128,
// TRIPLE-buffered (dist-2 prefetch, counted vmcnt), chunked XCD swizzle.
// ---------------------------------------------------------------------------
__global__ __launch_bounds__(256, 4) void gemmo_kernel(
    const bf16* __restrict__ A, const bf16* __restrict__ Bt,
    const float* __restrict__ bias, float* __restrict__ Out)
{
    __shared__ bf16 As[3][64 * 32];
    __shared__ bf16 Bs[3][128 * 32];

    const int hw      = blockIdx.x;
    const int logical = (hw & 7) * 64 + (hw >> 3);
    const int m0      = (logical >> 3) * 64;
    const int n0      = (logical & 7) * 128;

    const int tid = threadIdx.x, lane = tid & 63, w = tid >> 6;
    const int wm = w >> 1, wn = w & 1, g = lane >> 4, c = lane & 15;

    const int arow = w * 16 + (lane >> 2);
    const int brow = w * 32 + (lane >> 2);
    const int scol = (lane & 3) * 8;
    const bf16* Ag = A  + (size_t)(m0 + arow) * D_MODEL + scol;
    const bf16* Bg = Bt + (size_t)(n0 + brow) * D_MODEL + scol;

    f32x4 acc[2][4] = {};

#define OSTAGE(buf, kk)                                                         \
    do {                                                                        \
        gload16(Ag + (kk),                &As[buf][(w * 16) * 32]);             \
        gload16(Bg + (kk),                &Bs[buf][(w * 32) * 32]);             \
        gload16(Bg + 16 * D_MODEL + (kk), &Bs[buf][(w * 32 + 16) * 32]);        \
    } while (0)

    OSTAGE(0, 0);
    OSTAGE(1, 32);
    WAIT_VM(3);
    __builtin_amdgcn_s_barrier();

    int cur = 0;
    for (int t = 0; t < 32; ++t) {
        if (t + 2 < 32) {
            int pre = cur + 2; if (pre >= 3) pre -= 3;
            OSTAGE(pre, (t + 2) * 32);
        }

        bf16x8 a[2], b[4];
        #pragma unroll
        for (int i = 0; i < 2; i++) a[i] = *(const bf16x8*)&As[cur][(wm*32 + i*16 + c) * 32 + g*8];
        #pragma unroll
        for (int j = 0; j < 4; j++) b[j] = *(const bf16x8*)&Bs[cur][(wn*64 + j*16 + c) * 32 + g*8];

        __builtin_amdgcn_s_setprio(1);
        #pragma unroll
        for (int i = 0; i < 2; i++)
            #pragma unroll
            for (int j = 0; j < 4; j++)
                acc[i][j] = __builtin_amdgcn_mfma_f32_16x16x32_bf16(a[i], b[j], acc[i][j], 0, 0, 0);
        __builtin_amdgcn_s_setprio(0);

        if (t + 2 < 32) { WAIT_VM(3); }
        else            { WAIT_VM(0); }
        __builtin_amdgcn_s_barrier();
        cur = (cur + 1 == 3) ? 0 : cur + 1;
    }
#undef OSTAGE

    #pragma unroll
    for (int i = 0; i < 2; i++)
        #pragma unroll
        for (int j = 0; j < 4; j++) {
            const int ncol = n0 + wn*64 + j*16 + c;
            const float bb = bias[ncol];
            #pragma unroll
            for (int r = 0; r < 4; r++) {
                const int mrow = m0 + wm*32 + i*16 + g*4 + r;
                Out[(size_t)mrow * D_MODEL + ncol] = acc[i][j][r] + bb;
            }
        }
}

// ---------------------------------------------------------------------------
extern "C" void kernel_launch(void* const* d_in, const int* in_sizes, int n_in,
                              void* d_out, int out_size, void* d_ws, size_t ws_size,
                              hipStream_t stream) {
    const float* q     = (const float*)d_in[0];
    const float* k     = (const float*)d_in[1];
    const float* v     = (const float*)d_in[2];
    const float* Wq    = (const float*)d_in[3];
    const float* bq    = (const float*)d_in[4];
    const float* Wk    = (const float*)d_in[5];
    const float* bk    = (const float*)d_in[6];
    const float* Wv    = (const float*)d_in[7];
    const float* bv    = (const float*)d_in[8];
    const float* Wo    = (const float*)d_in[9];
    const float* bo    = (const float*)d_in[10];
    const float* alpha = (const float*)d_in[11];

    char* ws = (char*)d_ws;
    const size_t WBYTES = (size_t)D_MODEL * D_MODEL * sizeof(bf16);                // 2MB
    const size_t HBYTES = (size_t)B_SZ * N_HEADS * T_LEN * D_K * sizeof(bf16);     // 8MB
    const size_t NBYTES = (size_t)B_SZ * N_HEADS * T_LEN * sizeof(float);          // 256KB
    bf16* WtQ = (bf16*)ws;  ws += WBYTES;
    bf16* WtK = (bf16*)ws;  ws += WBYTES;
    bf16* WtV = (bf16*)ws;  ws += WBYTES;
    bf16* WtO = (bf16*)ws;  ws += WBYTES;
    bf16* qh  = (bf16*)ws;  ws += HBYTES;
    bf16* kh  = (bf16*)ws;  ws += HBYTES;
    bf16* vt  = (bf16*)ws;  ws += HBYTES;
    float* nq = (float*)ws; ws += NBYTES;
    float* nk = (float*)ws; ws += NBYTES;
    bf16* ao  = (bf16*)ws;  ws += HBYTES;   // attn out [B,T,D] bf16
    bf16* qb  = (bf16*)ws;  ws += HBYTES;   // q bf16
    bf16* kb  = (bf16*)ws;  ws += HBYTES;   // k bf16
    bf16* vb  = ao;                          // alias: vb dead before attn writes ao

    wt_kernel<<<dim3(32, 32, 4), dim3(32, 8), 0, stream>>>(
        Wq, Wk, Wv, Wo, WtQ, WtK, WtV, WtO);

    conv3_kernel<<<dim3(M_ROWS * D_MODEL / 8 / 256, 3), 256, 0, stream>>>(
        q, k, v, qb, kb, vb);

    proj_kernel<<<768, 256, 0, stream>>>(
        qb, kb, vb, WtQ, WtK, WtV, bq, bk, bv, qh, kh, vt, nq, nk);

    attn_kernel<<<512, 512, 0, stream>>>(qh, kh, vt, nq, nk, alpha, ao);

    gemmo_kernel<<<512, 256, 0, stream>>>(ao, WtO, bo, (float*)d_out);
}